// Round 1
// baseline (61.135 us; speedup 1.0000x reference)
//
#include <hip/hip_runtime.h>
#include <hip/hip_bf16.h>
#include <math.h>

typedef short bf16x8 __attribute__((ext_vector_type(8)));
typedef float f32x4 __attribute__((ext_vector_type(4)));
typedef unsigned short u16;

#define AS1(p) ((const __attribute__((address_space(1))) unsigned int*)(p))
#define AS3(p) ((__attribute__((address_space(3))) unsigned int*)(p))

__device__ __forceinline__ u16 f2bf(float f) {
  union { float f; unsigned u; } v; v.f = f;
  unsigned r = v.u + 0x7fffu + ((v.u >> 16) & 1u);  // RNE
  return (u16)(r >> 16);
}

// ---------- Kernel 0: Wt[f][k] = bf16(W[k][f]) (256x256) ----------
__global__ void k_wt(const float* __restrict__ W, u16* __restrict__ Wt) {
  int idx = blockIdx.x * 256 + threadIdx.x;
#pragma unroll
  for (int q = 0; q < 4; ++q) {
    int i = idx + q * 16384;
    int f = i & 255, k = i >> 8;
    Wt[f * 256 + k] = f2bf(W[k * 256 + f]);
  }
}

// ---------- Kernel A: ht[b][f][j] = bf16( (x @ W)[b,j,f] ) ----------
// grid 512 (BM=32 rows of global M=16384), 512 threads (8 waves, 2x4 of 16x64)
__global__ __launch_bounds__(512, 4) void k_xw(
    const float* __restrict__ x, const u16* __restrict__ Wt, u16* __restrict__ ht)
{
  __shared__ u16 Ab[2][32 * 64];    // x tile  [m][k]  bf16, XOR-swizzled
  __shared__ u16 Bb[2][256 * 64];   // Wt tile [f][k]  bf16, src-pre-swizzled

  const int tid = threadIdx.x;
  const int lane = tid & 63;
  const int wid = tid >> 6;
  const int wr = wid >> 2, wc = wid & 3;

  const long row0 = (long)blockIdx.x * 32;
  const int b = (int)(row0 >> 11);
  const int jloc = (int)(row0 & 2047);
  const float* xb = x + row0 * 256;
  u16* htb = ht + ((size_t)b << 19);   // b * 256 * 2048

  const int ar = tid >> 4;             // A-stage row 0..31
  const int ac = tid & 15;             // float4 slot
  const int awb = ar * 128 + ((ac * 8) ^ ((ar & 7) << 4));

  f32x4 acc[4] = {};

  auto stage = [&](int t, int bufi) {
    // A: x 32x64 fp32 -> bf16 (reg-staged, swizzled ds_write)
    const float4 v = *(const float4*)(xb + ar * 256 + t * 64 + ac * 4);
    short4 p;
    p.x = (short)f2bf(v.x); p.y = (short)f2bf(v.y);
    p.z = (short)f2bf(v.z); p.w = (short)f2bf(v.w);
    *(short4*)((char*)(&Ab[bufi][0]) + awb) = p;
    // B: Wt tile [256][64] via global_load_lds (pre-swizzled source)
#pragma unroll
    for (int q = 0; q < 4; ++q) {
      const int fbase = wid * 32 + q * 8;
      const int f = fbase + (lane >> 3);
      const char* src = (const char*)Wt + f * 512 + t * 128
                        + (((lane & 7) * 16) ^ ((f & 7) << 4));
      __builtin_amdgcn_global_load_lds(AS1(src),
          AS3((char*)(&Bb[bufi][0]) + fbase * 128), 16, 0, 0);
    }
  };

  auto compute = [&](int bufi) {
#pragma unroll
    for (int kk = 0; kk < 2; ++kk) {
      const int am = wr * 16 + (lane & 15);
      const bf16x8 a = *(const bf16x8*)((const char*)(&Ab[bufi][0])
          + am * 128 + ((kk * 64 + (lane >> 4) * 16) ^ ((am & 7) << 4)));
#pragma unroll
      for (int nf = 0; nf < 4; ++nf) {
        const int bn = wc * 64 + nf * 16 + (lane & 15);
        const bf16x8 bv = *(const bf16x8*)((const char*)(&Bb[bufi][0])
            + bn * 128 + ((kk * 64 + (lane >> 4) * 16) ^ ((bn & 7) << 4)));
        acc[nf] = __builtin_amdgcn_mfma_f32_16x16x32_bf16(a, bv, acc[nf], 0, 0, 0);
      }
    }
  };

  stage(0, 0);
  __syncthreads();
#pragma unroll 2
  for (int t = 0; t < 4; ++t) {
    const int cur = t & 1;
    if (t + 1 < 4) stage(t + 1, cur ^ 1);
    compute(cur);
    __syncthreads();
  }

  // epilogue: lane holds 4 consecutive j at fixed f -> 8B stores to ht[f][j]
  const int j0 = jloc + wr * 16 + ((lane >> 4) << 2);
#pragma unroll
  for (int nf = 0; nf < 4; ++nf) {
    const int f = wc * 64 + nf * 16 + (lane & 15);
    short4 p;
    p.x = (short)f2bf(acc[nf][0]);
    p.y = (short)f2bf(acc[nf][1]);
    p.z = (short)f2bf(acc[nf][2]);
    p.w = (short)f2bf(acc[nf][3]);
    *(short4*)(&htb[(size_t)f * 2048 + j0]) = p;
  }
}

// ---------- Kernel B: out = elu( (1/deg) * adj @ h ) ----------
// grid 512 = 8 batches x 64 row-blocks (BM=32); batch = bid%8 -> XCD-local h
__global__ __launch_bounds__(512, 4) void k_agg(
    const float* __restrict__ adj, const u16* __restrict__ ht, float* __restrict__ out)
{
  __shared__ u16 Ab[2][32 * 64];    // adj tile [i][j] bf16, XOR-swizzled
  __shared__ u16 Bb[2][256 * 64];   // ht tile  [f][j] bf16, src-pre-swizzled

  const int tid = threadIdx.x;
  const int lane = tid & 63;
  const int wid = tid >> 6;
  const int wr = wid >> 2, wc = wid & 3;

  const int b = blockIdx.x & 7;
  const int rb = blockIdx.x >> 3;
  const int row0 = rb * 32;

  const float* adjb = adj + ((size_t)b * 2048 + row0) * 2048;
  const u16* htb = ht + ((size_t)b << 19);
  float* outb = out + ((size_t)b * 2048 + row0) * 256;

  const int ar = tid >> 4;
  const int ac = tid & 15;
  const int awb = ar * 128 + ((ac * 8) ^ ((ar & 7) << 4));

  float deg = 0.f;
  f32x4 acc[4] = {};

  auto stage = [&](int t, int bufi) {
    const float4 v = *(const float4*)(adjb + (size_t)ar * 2048 + t * 64 + ac * 4);
    deg += v.x + v.y + v.z + v.w;          // adj is 0/1 -> exact rowsum
    short4 p;
    p.x = (short)f2bf(v.x); p.y = (short)f2bf(v.y);
    p.z = (short)f2bf(v.z); p.w = (short)f2bf(v.w);
    *(short4*)((char*)(&Ab[bufi][0]) + awb) = p;
#pragma unroll
    for (int q = 0; q < 4; ++q) {
      const int fbase = wid * 32 + q * 8;
      const int f = fbase + (lane >> 3);
      const char* src = (const char*)htb + (size_t)f * 4096 + t * 128
                        + (((lane & 7) * 16) ^ ((f & 7) << 4));
      __builtin_amdgcn_global_load_lds(AS1(src),
          AS3((char*)(&Bb[bufi][0]) + fbase * 128), 16, 0, 0);
    }
  };

  auto compute = [&](int bufi) {
#pragma unroll
    for (int kk = 0; kk < 2; ++kk) {
      const int am = wr * 16 + (lane & 15);
      const bf16x8 a = *(const bf16x8*)((const char*)(&Ab[bufi][0])
          + am * 128 + ((kk * 64 + (lane >> 4) * 16) ^ ((am & 7) << 4)));
#pragma unroll
      for (int nf = 0; nf < 4; ++nf) {
        const int bn = wc * 64 + nf * 16 + (lane & 15);
        const bf16x8 bv = *(const bf16x8*)((const char*)(&Bb[bufi][0])
            + bn * 128 + ((kk * 64 + (lane >> 4) * 16) ^ ((bn & 7) << 4)));
        acc[nf] = __builtin_amdgcn_mfma_f32_16x16x32_bf16(a, bv, acc[nf], 0, 0, 0);
      }
    }
  };

  stage(0, 0);
  __syncthreads();
#pragma unroll 2
  for (int t = 0; t < 32; ++t) {
    const int cur = t & 1;
    if (t + 1 < 32) stage(t + 1, cur ^ 1);
    compute(cur);
    __syncthreads();
  }

  // deg: reduce across the 16 lanes that loaded row `ar`
#pragma unroll
  for (int s = 1; s < 16; s <<= 1) deg += __shfl_xor(deg, s);
  float* degLds = (float*)&Ab[0][0];     // A-buffer dead now
  if ((tid & 15) == 0) degLds[ar] = deg;
  __syncthreads();

  const int j0 = wr * 16 + ((lane >> 4) << 2);
  float sc[4];
#pragma unroll
  for (int r = 0; r < 4; ++r) {
    const float d = degLds[j0 + r];
    sc[r] = d > 0.f ? 1.f / d : (1.f / 2048.f);
  }
#pragma unroll
  for (int nf = 0; nf < 4; ++nf) {
    const int f = wc * 64 + nf * 16 + (lane & 15);
#pragma unroll
    for (int r = 0; r < 4; ++r) {
      const float v = acc[nf][r] * sc[r];
      outb[(j0 + r) * 256 + f] = v > 0.f ? v : expm1f(v);
    }
  }
}

extern "C" void kernel_launch(void* const* d_in, const int* in_sizes, int n_in,
                              void* d_out, int out_size, void* d_ws, size_t ws_size,
                              hipStream_t stream) {
  const float* x   = (const float*)d_in[0];
  const float* adj = (const float*)d_in[1];
  const float* W   = (const float*)d_in[2];
  // d_in[3] ('a') is mathematically dead: softmax rows are constant over the
  // active (adj>0) entries, so attention = 1/deg regardless of e.
  float* out = (float*)d_out;

  u16* Wt = (u16*)d_ws;                          // 256*256*2   = 128 KB
  u16* ht = (u16*)((char*)d_ws + (131072));      // 8*256*2048*2 = 8 MB

  k_wt<<<64, 256, 0, stream>>>(W, Wt);
  k_xw<<<512, 512, 0, stream>>>(x, Wt, ht);
  k_agg<<<512, 512, 0, stream>>>(adj, ht, out);
}